// Round 2
// baseline (304.418 us; speedup 1.0000x reference)
//
#include <hip/hip_runtime.h>
#include <math.h>

// RetNetRelPosDeform2D: B=8,H=8,N1=N2=32,slen=1024,D=64
// Outputs (fp32, flat-concatenated):
//   sin_q [8,8,1024,64]  @ 0
//   cos_q [8,8,1024,64]  @ 4194304
//   sin_k [1024,64]      @ 8388608
//   cos_k [1024,64]      @ 8454144
//   mask  [8,8,1024,1024]@ 8519680
#define OFF_COSQ  4194304
#define OFF_SINK  8388608
#define OFF_COSK  8454144
#define OFF_MASK  8519680
#define NROWS     65536   // B*H*slen

typedef float floatx4 __attribute__((ext_vector_type(4)));

// Raw hardware exp2 (v_exp_f32). Named to avoid glibc's __exp2f symbol.
__device__ __forceinline__ float hexp2(float x) {
    return __builtin_amdgcn_exp2f(x);
}

__global__ __launch_bounds__(256) void retnet_fused_kernel(
    const float* __restrict__ offsets,   // [B,H,32,32,2]
    const float* __restrict__ angle,     // [64]
    const float* __restrict__ decay,     // [8]
    float* __restrict__ out)
{
    const int wave = blockIdx.x * 4 + (threadIdx.x >> 6); // one wave per query row
    const int lane = threadIdx.x & 63;
    // grid is exact: 16384 blocks * 4 waves == NROWS, no bounds check needed

    const int bh = wave >> 10;      // b*8+h
    const int s  = wave & 1023;     // i*32+j
    const int h  = bh & 7;
    const int i  = s >> 5;
    const int j  = s & 31;

    const float2 off = *(const float2*)(offsets + (wave << 1));
    const float i1q  = (float)i + off.x;     // deformed row index
    const float i2q  = (float)j + off.y;     // deformed col index
    const float dec  = decay[h];             // negative
    const float L    = dec * 1.44269504089f; // exp(dec*t) == exp2(L*t)

    // ---- closed-form row sums (geometric series) — no cross-lane ops ----
    // S(x) = [exp(d*(x-mc)) + exp(d*(mc+1-x)) - exp(d*(x+1)) - exp(d*(32-x))] / (1-exp(d))
    // with mc = clamp(floor(x), -1, 31); handles x outside [0,31] exactly.
    const float inv1mr = 1.0f / (1.0f - hexp2(L));
    const float m1 = fminf(fmaxf(floorf(i1q), -1.0f), 31.0f);
    const float S1 = (hexp2(L * (i1q - m1)) + hexp2(L * (m1 + 1.0f - i1q))
                    - hexp2(L * (i1q + 1.0f)) - hexp2(L * (32.0f - i1q))) * inv1mr;
    const float m2 = fminf(fmaxf(floorf(i2q), -1.0f), 31.0f);
    const float S2 = (hexp2(L * (i2q - m2)) + hexp2(L * (m2 + 1.0f - i2q))
                    - hexp2(L * (i2q + 1.0f)) - hexp2(L * (32.0f - i2q))) * inv1mr;
    const float invnorm = rsqrtf(S1 * S2);

    // ---- mask row FIRST (89% of all bytes; issue its stores asap) ----
    // float4 index f = k*64 + lane -> element e0 = 4*f;
    //   ii = e0>>5 = k*8 + (lane>>3), jj = e0&31 = (lane&7)*4 + c
    const int jj0 = (lane & 7) * 4;
    float e2a[4];
    #pragma unroll
    for (int c = 0; c < 4; ++c)
        e2a[c] = hexp2(L * fabsf(i2q - (float)(jj0 + c))) * invnorm;

    floatx4* mrow = (floatx4*)(out + OFF_MASK + (size_t)wave * 1024);
    #pragma unroll
    for (int k = 0; k < 4; ++k) {
        const int ii = k * 8 + (lane >> 3);
        const float e1 = hexp2(L * fabsf(i1q - (float)ii));
        floatx4 r;
        r.x = e1 * e2a[0];
        r.y = e1 * e2a[1];
        r.z = e1 * e2a[2];
        r.w = e1 * e2a[3];
        mrow[k * 64 + lane] = r;   // plain cached store (nt removed)
    }

    // ---- sin_q / cos_q (lane l handles dim d=l) ----
    const float ang = angle[lane];
    {
        float sq, cq;
        __sincosf((i1q + i2q) * ang, &sq, &cq);
        out[(size_t)wave * 64 + lane] = sq;
        out[OFF_COSQ + (size_t)wave * 64 + lane] = cq;
    }

    // ---- sin_k / cos_k: only the first 1024 rows (bh==0) emit them ----
    if (bh == 0) {
        float sk, ck;
        __sincosf((float)(i + j) * ang, &sk, &ck);
        out[OFF_SINK + (size_t)s * 64 + lane] = sk;
        out[OFF_COSK + (size_t)s * 64 + lane] = ck;
    }
}

extern "C" void kernel_launch(void* const* d_in, const int* in_sizes, int n_in,
                              void* d_out, int out_size, void* d_ws, size_t ws_size,
                              hipStream_t stream) {
    // inputs: [0]=slen (int, unused), [1]=offsets fp32 [8,8,32,32,2],
    //         [2]=angle fp32 [64], [3]=decay fp32 [8]
    const float* offsets = (const float*)d_in[1];
    const float* angle   = (const float*)d_in[2];
    const float* decay   = (const float*)d_in[3];
    float* out = (float*)d_out;

    const int blocks = NROWS / 4;  // 4 waves (rows) per 256-thread block
    retnet_fused_kernel<<<blocks, 256, 0, stream>>>(offsets, angle, decay, out);
}

// Round 3
// 301.900 us; speedup vs baseline: 1.0083x; 1.0083x over previous
//
#include <hip/hip_runtime.h>
#include <math.h>

// RetNetRelPosDeform2D: B=8,H=8,N1=N2=32,slen=1024,D=64
// Outputs (fp32, flat-concatenated):
//   sin_q [8,8,1024,64]  @ 0
//   cos_q [8,8,1024,64]  @ 4194304
//   sin_k [1024,64]      @ 8388608
//   cos_k [1024,64]      @ 8454144
//   mask  [8,8,1024,1024]@ 8519680
#define OFF_COSQ  4194304
#define OFF_SINK  8388608
#define OFF_COSK  8454144
#define OFF_MASK  8519680
#define NROWS     65536   // B*H*slen
#define NWAVES    8192    // 2048 blocks * 4 waves/block
#define RPW       8       // rows per wave (NROWS / NWAVES)

typedef float floatx4 __attribute__((ext_vector_type(4)));

// Raw hardware exp2 (v_exp_f32). Named to avoid glibc's __exp2f symbol.
__device__ __forceinline__ float hexp2(float x) {
    return __builtin_amdgcn_exp2f(x);
}

__global__ __launch_bounds__(256) void retnet_fused_kernel(
    const float* __restrict__ offsets,   // [B,H,32,32,2]
    const float* __restrict__ angle,     // [64]
    const float* __restrict__ decay,     // [8]
    float* __restrict__ out)
{
    const int wave0 = blockIdx.x * 4 + (threadIdx.x >> 6);
    const int lane  = threadIdx.x & 63;

    const float ang = angle[lane];       // row-invariant
    const int   jj0 = (lane & 7) * 4;    // row-invariant

    // Issue all per-row offset loads up-front (overlap their latency).
    float2 off[RPW];
    #pragma unroll
    for (int r = 0; r < RPW; ++r)
        off[r] = *(const float2*)(offsets + ((size_t)(wave0 + r * NWAVES) << 1));

    #pragma unroll
    for (int r = 0; r < RPW; ++r) {
        const int wave = wave0 + r * NWAVES;  // query row index
        const int bh = wave >> 10;            // b*8+h
        const int s  = wave & 1023;           // i*32+j
        const int h  = bh & 7;
        const int i  = s >> 5;
        const int j  = s & 31;

        const float i1q = (float)i + off[r].x;   // deformed row index
        const float i2q = (float)j + off[r].y;   // deformed col index
        const float dec = decay[h];              // negative
        const float L   = dec * 1.44269504089f;  // exp(dec*t) == exp2(L*t)

        // Closed-form row sums (geometric series) — no cross-lane ops.
        // S(x) = [e(x-mc) + e(mc+1-x) - e(x+1) - e(32-x)] / (1-e(1)),
        // e(t)=exp(dec*t), mc = clamp(floor(x), -1, 31).
        const float inv1mr = 1.0f / (1.0f - hexp2(L));
        const float m1 = fminf(fmaxf(floorf(i1q), -1.0f), 31.0f);
        const float S1 = (hexp2(L * (i1q - m1)) + hexp2(L * (m1 + 1.0f - i1q))
                        - hexp2(L * (i1q + 1.0f)) - hexp2(L * (32.0f - i1q))) * inv1mr;
        const float m2 = fminf(fmaxf(floorf(i2q), -1.0f), 31.0f);
        const float S2 = (hexp2(L * (i2q - m2)) + hexp2(L * (m2 + 1.0f - i2q))
                        - hexp2(L * (i2q + 1.0f)) - hexp2(L * (32.0f - i2q))) * inv1mr;
        const float invnorm = rsqrtf(S1 * S2);

        // Mask row (89% of bytes). float4 index f = k*64 + lane:
        //   ii = k*8 + (lane>>3), jj = (lane&7)*4 + c
        float e2a[4];
        #pragma unroll
        for (int c = 0; c < 4; ++c)
            e2a[c] = hexp2(L * fabsf(i2q - (float)(jj0 + c))) * invnorm;

        floatx4* mrow = (floatx4*)(out + OFF_MASK + (size_t)wave * 1024);
        #pragma unroll
        for (int k = 0; k < 4; ++k) {
            const int ii = k * 8 + (lane >> 3);
            const float e1 = hexp2(L * fabsf(i1q - (float)ii));
            floatx4 v;
            v.x = e1 * e2a[0];
            v.y = e1 * e2a[1];
            v.z = e1 * e2a[2];
            v.w = e1 * e2a[3];
            mrow[k * 64 + lane] = v;
        }

        // sin_q / cos_q (lane l handles dim d=l)
        {
            float sq, cq;
            __sincosf((i1q + i2q) * ang, &sq, &cq);
            out[(size_t)wave * 64 + lane] = sq;
            out[OFF_COSQ + (size_t)wave * 64 + lane] = cq;
        }

        // sin_k / cos_k: only rows with bh==0 (i.e. r==0 and wave0<1024)
        if (bh == 0) {
            float sk, ck;
            __sincosf((float)(i + j) * ang, &sk, &ck);
            out[OFF_SINK + (size_t)s * 64 + lane] = sk;
            out[OFF_COSK + (size_t)s * 64 + lane] = ck;
        }
    }
}

extern "C" void kernel_launch(void* const* d_in, const int* in_sizes, int n_in,
                              void* d_out, int out_size, void* d_ws, size_t ws_size,
                              hipStream_t stream) {
    // inputs: [0]=slen (int, unused), [1]=offsets fp32 [8,8,32,32,2],
    //         [2]=angle fp32 [64], [3]=decay fp32 [8]
    const float* offsets = (const float*)d_in[1];
    const float* angle   = (const float*)d_in[2];
    const float* decay   = (const float*)d_in[3];
    float* out = (float*)d_out;

    const int blocks = NWAVES / 4;  // 2048 blocks, grid-stride over 8 rows/wave
    retnet_fused_kernel<<<blocks, 256, 0, stream>>>(offsets, angle, decay, out);
}